// Round 12
// baseline (91.780 us; speedup 1.0000x reference)
//
#include <hip/hip_runtime.h>
#include <hip/hip_bf16.h>

// MultiHeadedAttention (namedtensor quirk): 64 heads x dim16, scores /1024,
// bool mask -> -1e9, softmax over keys.
// R12 = R11 with the mask-prefetch ordering bug fixed (extract mword from the
// CURRENT mq before the rolling quad update; R11 clobbered tiles 3/7/11).
// attn: in-register P (shfl_xor builds the 32x32x16 PV A-frag), PV B=[V|ones]
// -> O and row sums in one MFMA pair. GEMMs (BK=64 XOR-swizzle)/convert = R10.

typedef __hip_bfloat16 bf16;
typedef __attribute__((ext_vector_type(8))) short short8;
typedef __attribute__((ext_vector_type(4))) float f32x4;
typedef __attribute__((ext_vector_type(16))) float f32x16;

__device__ __forceinline__ unsigned short f2bf(float f) {
  union { float f; unsigned u; } x; x.f = f;
  unsigned r = x.u + 0x7FFFu + ((x.u >> 16) & 1u);   // RNE
  return (unsigned short)(r >> 16);
}

__device__ __forceinline__ unsigned cvt_pk_bf16(float lo, float hi) {
  unsigned r;
  asm("v_cvt_pk_bf16_f32 %0, %1, %2" : "=v"(r) : "v"(lo), "v"(hi));
  return r;
}

__device__ __forceinline__ float fast_exp2(float x) {
#if __has_builtin(__builtin_amdgcn_exp2f)
  return __builtin_amdgcn_exp2f(x);
#else
  return __expf(x * 0.6931471805599453f);
#endif
}

__device__ __forceinline__ float fast_rcp(float x) {
#if __has_builtin(__builtin_amdgcn_rcpf)
  return __builtin_amdgcn_rcpf(x);
#else
  return 1.0f / x;
#endif
}

// Async global->LDS, 16B per lane.
__device__ __forceinline__ void gload16(const void* g, void* l) {
#if __has_builtin(__builtin_amdgcn_global_load_lds)
  __builtin_amdgcn_global_load_lds(
      (const __attribute__((address_space(1))) unsigned*)g,
      (__attribute__((address_space(3))) unsigned*)l, 16, 0, 0);
#else
  *(uint4*)l = *(const uint4*)g;
#endif
}

// ---------------------------------------------------------------------------
// Fused convert + bitpack (R10 verbatim). z=0..2 inputs, z=3..6 weights (Wq
// scaled by log2(e)/1024), z=7 mask bitpack with per-block dtype detection.
__global__ void convert_all(
    const float* __restrict__ s0, const float* __restrict__ s1, const float* __restrict__ s2,
    const float* __restrict__ s3, const float* __restrict__ s4, const float* __restrict__ s5,
    const float* __restrict__ s6,
    bf16* __restrict__ d0, bf16* __restrict__ d1, bf16* __restrict__ d2,
    bf16* __restrict__ d3, bf16* __restrict__ d4, bf16* __restrict__ d5,
    bf16* __restrict__ d6,
    const unsigned char* __restrict__ mB, const int* __restrict__ mI,
    unsigned* __restrict__ mout) {
  const int z = blockIdx.y;
  if (z == 7) {
    if (blockIdx.x >= 256) return;
    __shared__ int sflag;
    if (threadIdx.x == 0) sflag = 0;
    __syncthreads();
    const int widx = blockIdx.x * 256 + threadIdx.x;   // 65536 words
    const int row = widx >> 5, kb = widx & 31;
    uchar4 v[8];
    const uchar4* p = (const uchar4*)(mB + (size_t)row * 1024 + kb * 32);
    unsigned any = 0;
#pragma unroll
    for (int j = 0; j < 8; ++j) { v[j] = p[j]; any |= (unsigned)v[j].y | (unsigned)v[j].z | (unsigned)v[j].w; }
    if (__ballot(any != 0)) { if ((threadIdx.x & 63) == 0) atomicOr(&sflag, 1); }
    __syncthreads();
    unsigned bits = 0;
    if (sflag) {   // bool mask
#pragma unroll
      for (int j = 0; j < 8; ++j) {
        bits |= ((unsigned)(v[j].x != 0) << (4 * j)) | ((unsigned)(v[j].y != 0) << (4 * j + 1))
              | ((unsigned)(v[j].z != 0) << (4 * j + 2)) | ((unsigned)(v[j].w != 0) << (4 * j + 3));
      }
    } else {       // int32 mask
      const int4* q = (const int4*)(mI + (size_t)row * 1024 + kb * 32);
#pragma unroll
      for (int j = 0; j < 8; ++j) {
        int4 u = q[j];
        bits |= ((unsigned)(u.x != 0) << (4 * j)) | ((unsigned)(u.y != 0) << (4 * j + 1))
              | ((unsigned)(u.z != 0) << (4 * j + 2)) | ((unsigned)(u.w != 0) << (4 * j + 3));
      }
    }
    const int bq = row >> 10, qb = (row & 1023) >> 5, qr = row & 31;
    mout[((((bq * 32 + qb) * 8 + (kb >> 2)) * 32 + qr) << 2) + (kb & 3)] = bits;
    return;
  }
  const float* s; bf16* d; int n8; float sc = 1.0f;
  if      (z == 0) { s = s0; d = d0; n8 = 262144; }
  else if (z == 1) { s = s1; d = d1; n8 = 262144; }
  else if (z == 2) { s = s2; d = d2; n8 = 262144; }
  else if (z == 3) { s = s3; d = d3; n8 = 131072; sc = 0.0014088818758681283f; }   // log2e/1024
  else if (z == 4) { s = s4; d = d4; n8 = 131072; }
  else if (z == 5) { s = s5; d = d5; n8 = 131072; }
  else             { s = s6; d = d6; n8 = 131072; }
  const int i = blockIdx.x * 256 + threadIdx.x;
  if (i >= n8) return;
  const f32x4* p = (const f32x4*)s + (size_t)i * 2;
  f32x4 a = p[0], b = p[1];
  uint4 o;
  o.x = cvt_pk_bf16(a[0] * sc, a[1] * sc); o.y = cvt_pk_bf16(a[2] * sc, a[3] * sc);
  o.z = cvt_pk_bf16(b[0] * sc, b[1] * sc); o.w = cvt_pk_bf16(b[2] * sc, b[3] * sc);
  ((uint4*)d)[i] = o;
}

// ---------------------------------------------------------------------------
// GEMM C = A * W^T, bf16, 128x64 tile, 4 waves, BK=64 (R10 verbatim).
__global__ __launch_bounds__(256) void gemm_qkv(
    const bf16* __restrict__ A0, const bf16* __restrict__ A1, const bf16* __restrict__ A2,
    const bf16* __restrict__ W0, const bf16* __restrict__ W1, const bf16* __restrict__ W2,
    bf16* __restrict__ C0, bf16* __restrict__ C1, bf16* __restrict__ C2) {
  __shared__ __align__(16) bf16 smem[12288];       // 24KB: A[128][64]+B[64][64]
  bf16* As = smem;
  bf16* Bs = smem + 8192;
  const int z = blockIdx.z;
  const bf16* __restrict__ A = (z == 0) ? A0 : (z == 1) ? A1 : A2;
  const bf16* __restrict__ W = (z == 0) ? W0 : (z == 1) ? W1 : W2;
  bf16* __restrict__ C = (z == 0) ? C0 : (z == 1) ? C1 : C2;
  const int tid = threadIdx.x, lane = tid & 63, w = tid >> 6;
  const int wr = (w >> 1) * 64, wc = (w & 1) * 32;
  const int row0 = blockIdx.y * 128, col0 = blockIdx.x * 64;
  const int l15 = lane & 15, kg = lane >> 4;
  const int l7 = l15 & 7;

  const bf16* ga[4]; const bf16* gb[2];
  bf16* la[4]; bf16* lb[2];
#pragma unroll
  for (int r = 0; r < 4; ++r) {
    const int idx = r * 256 + tid, row = idx >> 3, g = idx & 7;
    ga[r] = A + (size_t)(row0 + row) * 1024 + (g ^ (row & 7)) * 8;
    la[r] = As + idx * 8;
  }
#pragma unroll
  for (int r = 0; r < 2; ++r) {
    const int idx = r * 256 + tid, row = idx >> 3, g = idx & 7;
    gb[r] = W + (size_t)(col0 + row) * 1024 + (g ^ (row & 7)) * 8;
    lb[r] = Bs + idx * 8;
  }

  f32x4 acc[4][2];
#pragma unroll
  for (int m = 0; m < 4; ++m)
#pragma unroll
    for (int n = 0; n < 2; ++n)
#pragma unroll
      for (int j = 0; j < 4; ++j) acc[m][n][j] = 0.f;

  for (int t = 0; t < 16; ++t) {
    const int k0 = t * 64;
#pragma unroll
    for (int r = 0; r < 4; ++r) gload16(ga[r] + k0, la[r]);
#pragma unroll
    for (int r = 0; r < 2; ++r) gload16(gb[r] + k0, lb[r]);
    __syncthreads();
    short8 af[4][2], bfr[2][2];
#pragma unroll
    for (int m = 0; m < 4; ++m)
#pragma unroll
      for (int ks = 0; ks < 2; ++ks)
        af[m][ks] = *(const short8*)(&As[(wr + m * 16 + l15) * 64 + ((ks * 4 + kg) ^ l7) * 8]);
#pragma unroll
    for (int n = 0; n < 2; ++n)
#pragma unroll
      for (int ks = 0; ks < 2; ++ks)
        bfr[n][ks] = *(const short8*)(&Bs[(wc + n * 16 + l15) * 64 + ((ks * 4 + kg) ^ l7) * 8]);
#pragma unroll
    for (int ks = 0; ks < 2; ++ks)
#pragma unroll
      for (int m = 0; m < 4; ++m)
#pragma unroll
        for (int n = 0; n < 2; ++n)
          acc[m][n] = __builtin_amdgcn_mfma_f32_16x16x32_bf16(af[m][ks], bfr[n][ks], acc[m][n], 0, 0, 0);
    __syncthreads();
  }

  const int bb = row0 >> 10, srel0 = row0 & 1023;
  if (z == 2) {
    // LDS transpose then coalesced 1KB-tile stores: VT[bh][kb][d(16)][k(32)].
    bf16* T = smem;   // [64 e][136]
#pragma unroll
    for (int m = 0; m < 4; ++m)
#pragma unroll
      for (int n = 0; n < 2; ++n) {
        const int e = wc + n * 16 + l15;
        const int rb = wr + m * 16 + kg * 4;
        uint2 u;
        u.x = cvt_pk_bf16(acc[m][n][0], acc[m][n][1]);
        u.y = cvt_pk_bf16(acc[m][n][2], acc[m][n][3]);
        *(uint2*)(T + e * 136 + rb) = u;
      }
    __syncthreads();
#pragma unroll
    for (int i = 0; i < 4; ++i) {
      const int idx = i * 256 + tid;          // 1024 uint4
      const int tile = idx >> 6, within = idx & 63;
      const int hl = tile >> 2, kbl = tile & 3;
      const int e_sub = within >> 2, kq4 = within & 3;
      uint4 v = *(const uint4*)(T + (hl * 16 + e_sub) * 136 + kbl * 32 + kq4 * 8);
      const int h = (col0 >> 4) + hl;
      const size_t kb = (size_t)((srel0 >> 5) + kbl);
      *(uint4*)((unsigned short*)C + (((size_t)(bb * 64 + h) * 32 + kb) * 512 + e_sub * 32 + kq4 * 8)) = v;
    }
  } else if (z == 1) {
    // KT[bh][kb][k&31][d(16)] direct store.
#pragma unroll
    for (int m = 0; m < 4; ++m)
#pragma unroll
      for (int n = 0; n < 2; ++n) {
        const int ecol = wc + n * 16 + l15;
        const int h = (col0 >> 4) + (ecol >> 4), d = ecol & 15;
#pragma unroll
        for (int j = 0; j < 4; ++j) {
          const int s = srel0 + wr + m * 16 + kg * 4 + j;
          ((unsigned short*)C)[((size_t)(bb * 64 + h) * 32 + (s >> 5)) * 512 + (s & 31) * 16 + d] =
              f2bf(acc[m][n][j]);
        }
      }
  } else {
#pragma unroll
    for (int m = 0; m < 4; ++m)
#pragma unroll
      for (int n = 0; n < 2; ++n) {
        const int col = col0 + wc + n * 16 + l15;
#pragma unroll
        for (int j = 0; j < 4; ++j) {
          const int row = row0 + wr + m * 16 + kg * 4 + j;
          ((unsigned short*)C)[(size_t)row * 1024 + col] = f2bf(acc[m][n][j]);
        }
      }
  }
}

__global__ __launch_bounds__(256) void gemm_out(
    const bf16* __restrict__ A, const bf16* __restrict__ W, float* __restrict__ C) {
  __shared__ __align__(16) bf16 smem[12288];       // A[128][64]+B[64][64]
  bf16* As = smem;
  bf16* Bs = smem + 8192;
  const int tid = threadIdx.x, lane = tid & 63, w = tid >> 6;
  const int wr = (w >> 1) * 64, wc = (w & 1) * 32;
  const int row0 = blockIdx.y * 128, col0 = blockIdx.x * 64;
  const int l15 = lane & 15, kg = lane >> 4;
  const int l7 = l15 & 7;

  const bf16* ga[4]; const bf16* gb[2];
  bf16* la[4]; bf16* lb[2];
#pragma unroll
  for (int r = 0; r < 4; ++r) {
    const int idx = r * 256 + tid, row = idx >> 3, g = idx & 7;
    ga[r] = A + (size_t)(row0 + row) * 1024 + (g ^ (row & 7)) * 8;
    la[r] = As + idx * 8;
  }
#pragma unroll
  for (int r = 0; r < 2; ++r) {
    const int idx = r * 256 + tid, row = idx >> 3, g = idx & 7;
    gb[r] = W + (size_t)(col0 + row) * 1024 + (g ^ (row & 7)) * 8;
    lb[r] = Bs + idx * 8;
  }

  f32x4 acc[4][2];
#pragma unroll
  for (int m = 0; m < 4; ++m)
#pragma unroll
    for (int n = 0; n < 2; ++n)
#pragma unroll
      for (int j = 0; j < 4; ++j) acc[m][n][j] = 0.f;

  for (int t = 0; t < 16; ++t) {
    const int k0 = t * 64;
#pragma unroll
    for (int r = 0; r < 4; ++r) gload16(ga[r] + k0, la[r]);
#pragma unroll
    for (int r = 0; r < 2; ++r) gload16(gb[r] + k0, lb[r]);
    __syncthreads();
    short8 af[4][2], bfr[2][2];
#pragma unroll
    for (int m = 0; m < 4; ++m)
#pragma unroll
      for (int ks = 0; ks < 2; ++ks)
        af[m][ks] = *(const short8*)(&As[(wr + m * 16 + l15) * 64 + ((ks * 4 + kg) ^ l7) * 8]);
#pragma unroll
    for (int n = 0; n < 2; ++n)
#pragma unroll
      for (int ks = 0; ks < 2; ++ks)
        bfr[n][ks] = *(const short8*)(&Bs[(wc + n * 16 + l15) * 64 + ((ks * 4 + kg) ^ l7) * 8]);
#pragma unroll
    for (int ks = 0; ks < 2; ++ks)
#pragma unroll
      for (int m = 0; m < 4; ++m)
#pragma unroll
        for (int n = 0; n < 2; ++n)
          acc[m][n] = __builtin_amdgcn_mfma_f32_16x16x32_bf16(af[m][ks], bfr[n][ks], acc[m][n], 0, 0, 0);
    __syncthreads();
  }

#pragma unroll
  for (int m = 0; m < 4; ++m)
#pragma unroll
    for (int n = 0; n < 2; ++n) {
      const int col = col0 + wc + n * 16 + l15;
#pragma unroll
      for (int j = 0; j < 4; ++j) {
        const int row = row0 + wr + m * 16 + kg * 4 + j;
        C[(size_t)row * 1024 + col] = acc[m][n][j];
      }
    }
}

// ---------------------------------------------------------------------------
// Flash attention, swapped-QK, split-K x2, IN-REGISTER P (R11 structure, mask
// ordering fixed): after S^T = mfma32(K,Q), lane l31 holds P[q=l31][16 slots];
// cvt_pk + shfl_xor(32) + hi-select builds the 32x32x16 PV A-fragment.
// PV B = [V cols | ones cols] -> O and row sums in one MFMA pair.
__global__ __launch_bounds__(256) void attn_kernel(
    const bf16* __restrict__ Qp, const bf16* __restrict__ KT, const bf16* __restrict__ VT,
    const unsigned* __restrict__ mw, bf16* __restrict__ XO) {
  __shared__ float Cmb[128 * 17];   // 8.5KB combine area (stride 17 = no bank conflicts)
  const int tid = threadIdx.x, lane = tid & 63, w = tid >> 6;
  const int hi = lane >> 5, l31 = lane & 31, l15 = lane & 15;
  const int id = blockIdx.x;
  const int xcd = id & 7, grp = (id >> 3) & 15, qt = id >> 7;
  const int g = xcd * 16 + grp;
  const int b = g >> 6, h = g & 63;
  const int qg = w >> 1, kh = w & 1;
  const int q0 = qt * 64 + qg * 32;

  const short8 qf = *(const short8*)(Qp + ((size_t)(b * 1024 + q0 + l31)) * 1024 + h * 16 + hi * 8);
  const bf16* __restrict__ Kb = KT + ((size_t)(b * 64 + h) * 32) * 512;
  const bf16* __restrict__ Vb = VT + ((size_t)(b * 64 + h) * 32) * 512;
  const uint4* __restrict__ Mq =
      (const uint4*)mw + ((size_t)((b * 32 + (q0 >> 5)) * 8 + kh * 4)) * 32 + l31;
  const int sh4 = hi * 4;

  f32x16 acc, Z;
#pragma unroll
  for (int i = 0; i < 16; ++i) { acc[i] = 0.f; Z[i] = 0.f; }
  short8 ones;
#pragma unroll
  for (int i = 0; i < 8; ++i) ones[i] = (short)0x3F80;   // bf16 1.0

  // K prefetch (tile 0)
  short8 kf = *(const short8*)(Kb + (size_t)(kh * 16) * 512 + l31 * 16 + hi * 8);
  uint4 mq = Mq[0];

#pragma unroll
  for (int t = 0; t < 16; ++t) {
    const int kbg = kh * 16 + t;
    // FIX (R11 bug): extract this tile's mask word from the CURRENT quad
    // BEFORE the rolling prefetch overwrites mq.
    const unsigned mword =
        (((t & 3) == 0) ? mq.x : ((t & 3) == 1) ? mq.y : ((t & 3) == 2) ? mq.z : mq.w) >> sh4;
    // prefetch next K tile + next mask quad
    short8 kfn;
    if (t < 15) kfn = *(const short8*)(Kb + (size_t)(kbg + 1) * 512 + l31 * 16 + hi * 8);
    if ((t & 3) == 3 && t < 15) mq = Mq[(t / 4 + 1) * 32];
    // V for this tile (issued early; consumed after frag build)
    const bf16* vt = Vb + (size_t)kbg * 512 + l15 * 32 + hi * 8;
    const short8 vraw1 = *(const short8*)(vt);
    const short8 vraw2 = *(const short8*)(vt + 16);

    f32x16 S = __builtin_amdgcn_mfma_f32_32x32x16_bf16(kf, qf, Z, 0, 0, 0);
    // lane holds S^T[k = kbg*32 + 8g + 4hi + j][q = q0 + l31], reg r = 4g + j

    unsigned c[8], sw[8];
#pragma unroll
    for (int gg = 0; gg < 4; ++gg) {
      const float p0 = (mword & (1u << (8 * gg + 0))) ? 0.f : fast_exp2(S[4 * gg + 0]);
      const float p1 = (mword & (1u << (8 * gg + 1))) ? 0.f : fast_exp2(S[4 * gg + 1]);
      const float p2 = (mword & (1u << (8 * gg + 2))) ? 0.f : fast_exp2(S[4 * gg + 2]);
      const float p3 = (mword & (1u << (8 * gg + 3))) ? 0.f : fast_exp2(S[4 * gg + 3]);
      c[2 * gg]     = cvt_pk_bf16(p0, p1);   // k = 8g+4hi+{0,1}
      c[2 * gg + 1] = cvt_pk_bf16(p2, p3);   // k = 8g+4hi+{2,3}
    }
#pragma unroll
    for (int i = 0; i < 8; ++i) sw[i] = (unsigned)__shfl_xor((int)c[i], 32, 64);

    // A-frags: lane (l31,hi) holds P[q=l31][kk=hi*8+j] for kk-range per frag.
    uint4 fa1, fa2;
    fa1.x = hi ? sw[2] : c[0];  fa1.y = hi ? sw[3] : c[1];
    fa1.z = hi ? c[2]  : sw[0]; fa1.w = hi ? c[3]  : sw[1];
    fa2.x = hi ? sw[6] : c[4];  fa2.y = hi ? sw[7] : c[5];
    fa2.z = hi ? c[6]  : sw[4]; fa2.w = hi ? c[7]  : sw[5];
    short8 A1 = *(const short8*)&fa1;
    short8 A2 = *(const short8*)&fa2;

    // B-frags: cols 0..15 = V[k][d=l31], cols 16..31 = 1.0 (row-sum columns)
    const short8 vb1 = (l31 < 16) ? vraw1 : ones;
    const short8 vb2 = (l31 < 16) ? vraw2 : ones;

    __builtin_amdgcn_s_setprio(1);
    acc = __builtin_amdgcn_mfma_f32_32x32x16_bf16(A1, vb1, acc, 0, 0, 0);
    acc = __builtin_amdgcn_mfma_f32_32x32x16_bf16(A2, vb2, acc, 0, 0, 0);
    __builtin_amdgcn_s_setprio(0);
    kf = kfn;
  }

  // Split-K combine through LDS, then normalize+store (kh==0 waves).
  __syncthreads();
  if (kh) {
    float* dst = Cmb + ((size_t)(qg * 64 + lane)) * 17;
#pragma unroll
    for (int j = 0; j < 16; ++j) dst[j] = acc[j];
  }
  __syncthreads();
  if (!kh) {
    const float* src = Cmb + ((size_t)(qg * 64 + lane)) * 17;
    float o[16];
#pragma unroll
    for (int j = 0; j < 16; ++j) o[j] = acc[j] + src[j];
#pragma unroll
    for (int r = 0; r < 16; ++r) {
      const float s = __shfl_xor(o[r], 16, 64);   // lanes l31<16 receive row sum
      if (l31 < 16) {
        const int q = (r & 3) + 8 * (r >> 2) + 4 * hi;
        ((unsigned short*)XO)[((size_t)(b * 1024 + q0 + q)) * 1024 + h * 16 + l31] =
            f2bf(o[r] * fast_rcp(s));
      }
    }
  }
}

// ---------------------------------------------------------------------------
extern "C" void kernel_launch(void* const* d_in, const int* in_sizes, int n_in,
                              void* d_out, int out_size, void* d_ws, size_t ws_size,
                              hipStream_t stream) {
  const float* query = (const float*)d_in[0];
  const float* key   = (const float*)d_in[1];
  const float* value = (const float*)d_in[2];
  const void*  mask  = d_in[3];
  const float* Wq = (const float*)d_in[4];
  const float* Wk = (const float*)d_in[5];
  const float* Wv = (const float*)d_in[6];
  const float* Wo = (const float*)d_in[7];
  float* out = (float*)d_out;

  char* ws = (char*)d_ws;
  const size_t MB = 1024 * 1024;
  unsigned* mbits = (unsigned*)(ws + 4096);          // 256 KB
  bf16* Qb  = (bf16*)(ws + 4096 + 262144);           // converted inputs, 4 MB each
  bf16* Kb  = Qb + 2 * MB;
  bf16* Vb  = Kb + 2 * MB;
  bf16* Wqb = Vb + 2 * MB;                            // converted weights, 2 MB each
  bf16* Wkb = Wqb + MB;
  bf16* Wvb = Wkb + MB;
  bf16* Wob = Wvb + MB;
  bf16* Qp  = Wob + MB;                               // Q projection, 4 MB
  bf16* KTl = Qp + 2 * MB;                            // K per-head tiles
  bf16* VTl = KTl + 2 * MB;                           // V per-head tiles
  bf16* XO  = VTl + 2 * MB;                           // attn output

  convert_all<<<dim3(1024, 8), 256, 0, stream>>>(query, key, value, Wq, Wk, Wv, Wo,
                                                 Qb, Kb, Vb, Wqb, Wkb, Wvb, Wob,
                                                 (const unsigned char*)mask, (const int*)mask,
                                                 mbits);
  gemm_qkv<<<dim3(16, 16, 3), 256, 0, stream>>>(Qb, Kb, Vb, Wqb, Wkb, Wvb, Qp, KTl, VTl);
  attn_kernel<<<dim3(2048), 256, 0, stream>>>(Qp, KTl, VTl, mbits, XO);
  gemm_out<<<dim3(16, 16), 256, 0, stream>>>(XO, Wob, out);
}

// Round 13
// 90.272 us; speedup vs baseline: 1.0167x; 1.0167x over previous
//
#include <hip/hip_runtime.h>
#include <hip/hip_bf16.h>

// MultiHeadedAttention (namedtensor quirk): 64 heads x dim16, scores /1024,
// bool mask -> -1e9, softmax over keys.
// R13 = R12 with the lane^32 exchange moved from shfl_xor (ds_bpermute, DS
// pipe) to v_permlane32_swap_b32 (VALU): r0={a.lo,b.lo}, r1={a.hi,b.hi} means
// swap(c0,c2) directly yields PV A-frag words (x,z) — 4 swaps replace
// 8 bpermute + 8 cndmask. GEMMs (BK=64 XOR-swizzle)/convert = R10 verbatim.

typedef __hip_bfloat16 bf16;
typedef __attribute__((ext_vector_type(8))) short short8;
typedef __attribute__((ext_vector_type(4))) float f32x4;
typedef __attribute__((ext_vector_type(16))) float f32x16;
typedef __attribute__((ext_vector_type(2))) unsigned uintx2;

__device__ __forceinline__ unsigned short f2bf(float f) {
  union { float f; unsigned u; } x; x.f = f;
  unsigned r = x.u + 0x7FFFu + ((x.u >> 16) & 1u);   // RNE
  return (unsigned short)(r >> 16);
}

__device__ __forceinline__ unsigned cvt_pk_bf16(float lo, float hi) {
  unsigned r;
  asm("v_cvt_pk_bf16_f32 %0, %1, %2" : "=v"(r) : "v"(lo), "v"(hi));
  return r;
}

__device__ __forceinline__ float fast_exp2(float x) {
#if __has_builtin(__builtin_amdgcn_exp2f)
  return __builtin_amdgcn_exp2f(x);
#else
  return __expf(x * 0.6931471805599453f);
#endif
}

__device__ __forceinline__ float fast_rcp(float x) {
#if __has_builtin(__builtin_amdgcn_rcpf)
  return __builtin_amdgcn_rcpf(x);
#else
  return 1.0f / x;
#endif
}

// Exchange halves: after call, a = {a.lo-lanes, b.lo-lanes}, b = {a.hi, b.hi}.
__device__ __forceinline__ void plswap(unsigned& a, unsigned& b, int hi) {
#if __has_builtin(__builtin_amdgcn_permlane32_swap)
  uintx2 r = __builtin_amdgcn_permlane32_swap(a, b, false, false);
  a = r[0]; b = r[1];
#else
  const unsigned sa = (unsigned)__shfl_xor((int)a, 32, 64);
  const unsigned sb = (unsigned)__shfl_xor((int)b, 32, 64);
  a = hi ? sb : a;   // lanes>=32 get b's low-lane value
  b = hi ? b : sa;   // lanes<32 get a's high-lane value
#endif
}

// Async global->LDS, 16B per lane.
__device__ __forceinline__ void gload16(const void* g, void* l) {
#if __has_builtin(__builtin_amdgcn_global_load_lds)
  __builtin_amdgcn_global_load_lds(
      (const __attribute__((address_space(1))) unsigned*)g,
      (__attribute__((address_space(3))) unsigned*)l, 16, 0, 0);
#else
  *(uint4*)l = *(const uint4*)g;
#endif
}

// ---------------------------------------------------------------------------
// Fused convert + bitpack (R10 verbatim). z=0..2 inputs, z=3..6 weights (Wq
// scaled by log2(e)/1024), z=7 mask bitpack with per-block dtype detection.
__global__ void convert_all(
    const float* __restrict__ s0, const float* __restrict__ s1, const float* __restrict__ s2,
    const float* __restrict__ s3, const float* __restrict__ s4, const float* __restrict__ s5,
    const float* __restrict__ s6,
    bf16* __restrict__ d0, bf16* __restrict__ d1, bf16* __restrict__ d2,
    bf16* __restrict__ d3, bf16* __restrict__ d4, bf16* __restrict__ d5,
    bf16* __restrict__ d6,
    const unsigned char* __restrict__ mB, const int* __restrict__ mI,
    unsigned* __restrict__ mout) {
  const int z = blockIdx.y;
  if (z == 7) {
    if (blockIdx.x >= 256) return;
    __shared__ int sflag;
    if (threadIdx.x == 0) sflag = 0;
    __syncthreads();
    const int widx = blockIdx.x * 256 + threadIdx.x;   // 65536 words
    const int row = widx >> 5, kb = widx & 31;
    uchar4 v[8];
    const uchar4* p = (const uchar4*)(mB + (size_t)row * 1024 + kb * 32);
    unsigned any = 0;
#pragma unroll
    for (int j = 0; j < 8; ++j) { v[j] = p[j]; any |= (unsigned)v[j].y | (unsigned)v[j].z | (unsigned)v[j].w; }
    if (__ballot(any != 0)) { if ((threadIdx.x & 63) == 0) atomicOr(&sflag, 1); }
    __syncthreads();
    unsigned bits = 0;
    if (sflag) {   // bool mask
#pragma unroll
      for (int j = 0; j < 8; ++j) {
        bits |= ((unsigned)(v[j].x != 0) << (4 * j)) | ((unsigned)(v[j].y != 0) << (4 * j + 1))
              | ((unsigned)(v[j].z != 0) << (4 * j + 2)) | ((unsigned)(v[j].w != 0) << (4 * j + 3));
      }
    } else {       // int32 mask
      const int4* q = (const int4*)(mI + (size_t)row * 1024 + kb * 32);
#pragma unroll
      for (int j = 0; j < 8; ++j) {
        int4 u = q[j];
        bits |= ((unsigned)(u.x != 0) << (4 * j)) | ((unsigned)(u.y != 0) << (4 * j + 1))
              | ((unsigned)(u.z != 0) << (4 * j + 2)) | ((unsigned)(u.w != 0) << (4 * j + 3));
      }
    }
    const int bq = row >> 10, qb = (row & 1023) >> 5, qr = row & 31;
    mout[((((bq * 32 + qb) * 8 + (kb >> 2)) * 32 + qr) << 2) + (kb & 3)] = bits;
    return;
  }
  const float* s; bf16* d; int n8; float sc = 1.0f;
  if      (z == 0) { s = s0; d = d0; n8 = 262144; }
  else if (z == 1) { s = s1; d = d1; n8 = 262144; }
  else if (z == 2) { s = s2; d = d2; n8 = 262144; }
  else if (z == 3) { s = s3; d = d3; n8 = 131072; sc = 0.0014088818758681283f; }   // log2e/1024
  else if (z == 4) { s = s4; d = d4; n8 = 131072; }
  else if (z == 5) { s = s5; d = d5; n8 = 131072; }
  else             { s = s6; d = d6; n8 = 131072; }
  const int i = blockIdx.x * 256 + threadIdx.x;
  if (i >= n8) return;
  const f32x4* p = (const f32x4*)s + (size_t)i * 2;
  f32x4 a = p[0], b = p[1];
  uint4 o;
  o.x = cvt_pk_bf16(a[0] * sc, a[1] * sc); o.y = cvt_pk_bf16(a[2] * sc, a[3] * sc);
  o.z = cvt_pk_bf16(b[0] * sc, b[1] * sc); o.w = cvt_pk_bf16(b[2] * sc, b[3] * sc);
  ((uint4*)d)[i] = o;
}

// ---------------------------------------------------------------------------
// GEMM C = A * W^T, bf16, 128x64 tile, 4 waves, BK=64 (R10 verbatim).
__global__ __launch_bounds__(256) void gemm_qkv(
    const bf16* __restrict__ A0, const bf16* __restrict__ A1, const bf16* __restrict__ A2,
    const bf16* __restrict__ W0, const bf16* __restrict__ W1, const bf16* __restrict__ W2,
    bf16* __restrict__ C0, bf16* __restrict__ C1, bf16* __restrict__ C2) {
  __shared__ __align__(16) bf16 smem[12288];       // 24KB: A[128][64]+B[64][64]
  bf16* As = smem;
  bf16* Bs = smem + 8192;
  const int z = blockIdx.z;
  const bf16* __restrict__ A = (z == 0) ? A0 : (z == 1) ? A1 : A2;
  const bf16* __restrict__ W = (z == 0) ? W0 : (z == 1) ? W1 : W2;
  bf16* __restrict__ C = (z == 0) ? C0 : (z == 1) ? C1 : C2;
  const int tid = threadIdx.x, lane = tid & 63, w = tid >> 6;
  const int wr = (w >> 1) * 64, wc = (w & 1) * 32;
  const int row0 = blockIdx.y * 128, col0 = blockIdx.x * 64;
  const int l15 = lane & 15, kg = lane >> 4;
  const int l7 = l15 & 7;

  const bf16* ga[4]; const bf16* gb[2];
  bf16* la[4]; bf16* lb[2];
#pragma unroll
  for (int r = 0; r < 4; ++r) {
    const int idx = r * 256 + tid, row = idx >> 3, g = idx & 7;
    ga[r] = A + (size_t)(row0 + row) * 1024 + (g ^ (row & 7)) * 8;
    la[r] = As + idx * 8;
  }
#pragma unroll
  for (int r = 0; r < 2; ++r) {
    const int idx = r * 256 + tid, row = idx >> 3, g = idx & 7;
    gb[r] = W + (size_t)(col0 + row) * 1024 + (g ^ (row & 7)) * 8;
    lb[r] = Bs + idx * 8;
  }

  f32x4 acc[4][2];
#pragma unroll
  for (int m = 0; m < 4; ++m)
#pragma unroll
    for (int n = 0; n < 2; ++n)
#pragma unroll
      for (int j = 0; j < 4; ++j) acc[m][n][j] = 0.f;

  for (int t = 0; t < 16; ++t) {
    const int k0 = t * 64;
#pragma unroll
    for (int r = 0; r < 4; ++r) gload16(ga[r] + k0, la[r]);
#pragma unroll
    for (int r = 0; r < 2; ++r) gload16(gb[r] + k0, lb[r]);
    __syncthreads();
    short8 af[4][2], bfr[2][2];
#pragma unroll
    for (int m = 0; m < 4; ++m)
#pragma unroll
      for (int ks = 0; ks < 2; ++ks)
        af[m][ks] = *(const short8*)(&As[(wr + m * 16 + l15) * 64 + ((ks * 4 + kg) ^ l7) * 8]);
#pragma unroll
    for (int n = 0; n < 2; ++n)
#pragma unroll
      for (int ks = 0; ks < 2; ++ks)
        bfr[n][ks] = *(const short8*)(&Bs[(wc + n * 16 + l15) * 64 + ((ks * 4 + kg) ^ l7) * 8]);
#pragma unroll
    for (int ks = 0; ks < 2; ++ks)
#pragma unroll
      for (int m = 0; m < 4; ++m)
#pragma unroll
        for (int n = 0; n < 2; ++n)
          acc[m][n] = __builtin_amdgcn_mfma_f32_16x16x32_bf16(af[m][ks], bfr[n][ks], acc[m][n], 0, 0, 0);
    __syncthreads();
  }

  const int bb = row0 >> 10, srel0 = row0 & 1023;
  if (z == 2) {
    // LDS transpose then coalesced 1KB-tile stores: VT[bh][kb][d(16)][k(32)].
    bf16* T = smem;   // [64 e][136]
#pragma unroll
    for (int m = 0; m < 4; ++m)
#pragma unroll
      for (int n = 0; n < 2; ++n) {
        const int e = wc + n * 16 + l15;
        const int rb = wr + m * 16 + kg * 4;
        uint2 u;
        u.x = cvt_pk_bf16(acc[m][n][0], acc[m][n][1]);
        u.y = cvt_pk_bf16(acc[m][n][2], acc[m][n][3]);
        *(uint2*)(T + e * 136 + rb) = u;
      }
    __syncthreads();
#pragma unroll
    for (int i = 0; i < 4; ++i) {
      const int idx = i * 256 + tid;          // 1024 uint4
      const int tile = idx >> 6, within = idx & 63;
      const int hl = tile >> 2, kbl = tile & 3;
      const int e_sub = within >> 2, kq4 = within & 3;
      uint4 v = *(const uint4*)(T + (hl * 16 + e_sub) * 136 + kbl * 32 + kq4 * 8);
      const int h = (col0 >> 4) + hl;
      const size_t kb = (size_t)((srel0 >> 5) + kbl);
      *(uint4*)((unsigned short*)C + (((size_t)(bb * 64 + h) * 32 + kb) * 512 + e_sub * 32 + kq4 * 8)) = v;
    }
  } else if (z == 1) {
    // KT[bh][kb][k&31][d(16)] direct store.
#pragma unroll
    for (int m = 0; m < 4; ++m)
#pragma unroll
      for (int n = 0; n < 2; ++n) {
        const int ecol = wc + n * 16 + l15;
        const int h = (col0 >> 4) + (ecol >> 4), d = ecol & 15;
#pragma unroll
        for (int j = 0; j < 4; ++j) {
          const int s = srel0 + wr + m * 16 + kg * 4 + j;
          ((unsigned short*)C)[((size_t)(bb * 64 + h) * 32 + (s >> 5)) * 512 + (s & 31) * 16 + d] =
              f2bf(acc[m][n][j]);
        }
      }
  } else {
#pragma unroll
    for (int m = 0; m < 4; ++m)
#pragma unroll
      for (int n = 0; n < 2; ++n) {
        const int col = col0 + wc + n * 16 + l15;
#pragma unroll
        for (int j = 0; j < 4; ++j) {
          const int row = row0 + wr + m * 16 + kg * 4 + j;
          ((unsigned short*)C)[(size_t)row * 1024 + col] = f2bf(acc[m][n][j]);
        }
      }
  }
}

__global__ __launch_bounds__(256) void gemm_out(
    const bf16* __restrict__ A, const bf16* __restrict__ W, float* __restrict__ C) {
  __shared__ __align__(16) bf16 smem[12288];       // A[128][64]+B[64][64]
  bf16* As = smem;
  bf16* Bs = smem + 8192;
  const int tid = threadIdx.x, lane = tid & 63, w = tid >> 6;
  const int wr = (w >> 1) * 64, wc = (w & 1) * 32;
  const int row0 = blockIdx.y * 128, col0 = blockIdx.x * 64;
  const int l15 = lane & 15, kg = lane >> 4;
  const int l7 = l15 & 7;

  const bf16* ga[4]; const bf16* gb[2];
  bf16* la[4]; bf16* lb[2];
#pragma unroll
  for (int r = 0; r < 4; ++r) {
    const int idx = r * 256 + tid, row = idx >> 3, g = idx & 7;
    ga[r] = A + (size_t)(row0 + row) * 1024 + (g ^ (row & 7)) * 8;
    la[r] = As + idx * 8;
  }
#pragma unroll
  for (int r = 0; r < 2; ++r) {
    const int idx = r * 256 + tid, row = idx >> 3, g = idx & 7;
    gb[r] = W + (size_t)(col0 + row) * 1024 + (g ^ (row & 7)) * 8;
    lb[r] = Bs + idx * 8;
  }

  f32x4 acc[4][2];
#pragma unroll
  for (int m = 0; m < 4; ++m)
#pragma unroll
    for (int n = 0; n < 2; ++n)
#pragma unroll
      for (int j = 0; j < 4; ++j) acc[m][n][j] = 0.f;

  for (int t = 0; t < 16; ++t) {
    const int k0 = t * 64;
#pragma unroll
    for (int r = 0; r < 4; ++r) gload16(ga[r] + k0, la[r]);
#pragma unroll
    for (int r = 0; r < 2; ++r) gload16(gb[r] + k0, lb[r]);
    __syncthreads();
    short8 af[4][2], bfr[2][2];
#pragma unroll
    for (int m = 0; m < 4; ++m)
#pragma unroll
      for (int ks = 0; ks < 2; ++ks)
        af[m][ks] = *(const short8*)(&As[(wr + m * 16 + l15) * 64 + ((ks * 4 + kg) ^ l7) * 8]);
#pragma unroll
    for (int n = 0; n < 2; ++n)
#pragma unroll
      for (int ks = 0; ks < 2; ++ks)
        bfr[n][ks] = *(const short8*)(&Bs[(wc + n * 16 + l15) * 64 + ((ks * 4 + kg) ^ l7) * 8]);
#pragma unroll
    for (int ks = 0; ks < 2; ++ks)
#pragma unroll
      for (int m = 0; m < 4; ++m)
#pragma unroll
        for (int n = 0; n < 2; ++n)
          acc[m][n] = __builtin_amdgcn_mfma_f32_16x16x32_bf16(af[m][ks], bfr[n][ks], acc[m][n], 0, 0, 0);
    __syncthreads();
  }

#pragma unroll
  for (int m = 0; m < 4; ++m)
#pragma unroll
    for (int n = 0; n < 2; ++n) {
      const int col = col0 + wc + n * 16 + l15;
#pragma unroll
      for (int j = 0; j < 4; ++j) {
        const int row = row0 + wr + m * 16 + kg * 4 + j;
        C[(size_t)row * 1024 + col] = acc[m][n][j];
      }
    }
}

// ---------------------------------------------------------------------------
// Flash attention, swapped-QK, split-K x2, in-register P. The lane^32
// exchange uses permlane32_swap: swap(c0,c2) -> (fa.x, fa.z) directly.
__global__ __launch_bounds__(256) void attn_kernel(
    const bf16* __restrict__ Qp, const bf16* __restrict__ KT, const bf16* __restrict__ VT,
    const unsigned* __restrict__ mw, bf16* __restrict__ XO) {
  __shared__ float Cmb[128 * 17];   // 8.5KB combine area (stride 17 = no bank conflicts)
  const int tid = threadIdx.x, lane = tid & 63, w = tid >> 6;
  const int hi = lane >> 5, l31 = lane & 31, l15 = lane & 15;
  const int id = blockIdx.x;
  const int xcd = id & 7, grp = (id >> 3) & 15, qt = id >> 7;
  const int g = xcd * 16 + grp;
  const int b = g >> 6, h = g & 63;
  const int qg = w >> 1, kh = w & 1;
  const int q0 = qt * 64 + qg * 32;

  const short8 qf = *(const short8*)(Qp + ((size_t)(b * 1024 + q0 + l31)) * 1024 + h * 16 + hi * 8);
  const bf16* __restrict__ Kb = KT + ((size_t)(b * 64 + h) * 32) * 512;
  const bf16* __restrict__ Vb = VT + ((size_t)(b * 64 + h) * 32) * 512;
  const uint4* __restrict__ Mq =
      (const uint4*)mw + ((size_t)((b * 32 + (q0 >> 5)) * 8 + kh * 4)) * 32 + l31;
  const int sh4 = hi * 4;

  f32x16 acc, Z;
#pragma unroll
  for (int i = 0; i < 16; ++i) { acc[i] = 0.f; Z[i] = 0.f; }
  short8 ones;
#pragma unroll
  for (int i = 0; i < 8; ++i) ones[i] = (short)0x3F80;   // bf16 1.0

  // K prefetch (tile 0)
  short8 kf = *(const short8*)(Kb + (size_t)(kh * 16) * 512 + l31 * 16 + hi * 8);
  uint4 mq = Mq[0];

#pragma unroll
  for (int t = 0; t < 16; ++t) {
    const int kbg = kh * 16 + t;
    // extract this tile's mask word BEFORE the rolling prefetch updates mq
    const unsigned mword =
        (((t & 3) == 0) ? mq.x : ((t & 3) == 1) ? mq.y : ((t & 3) == 2) ? mq.z : mq.w) >> sh4;
    short8 kfn;
    if (t < 15) kfn = *(const short8*)(Kb + (size_t)(kbg + 1) * 512 + l31 * 16 + hi * 8);
    if ((t & 3) == 3 && t < 15) mq = Mq[(t / 4 + 1) * 32];
    const bf16* vt = Vb + (size_t)kbg * 512 + l15 * 32 + hi * 8;
    const short8 vraw1 = *(const short8*)(vt);
    const short8 vraw2 = *(const short8*)(vt + 16);

    f32x16 S = __builtin_amdgcn_mfma_f32_32x32x16_bf16(kf, qf, Z, 0, 0, 0);
    // lane holds S^T[k = kbg*32 + 8g + 4hi + j][q = q0 + l31], reg r = 4g + j

    unsigned c[8];
#pragma unroll
    for (int gg = 0; gg < 4; ++gg) {
      const float p0 = (mword & (1u << (8 * gg + 0))) ? 0.f : fast_exp2(S[4 * gg + 0]);
      const float p1 = (mword & (1u << (8 * gg + 1))) ? 0.f : fast_exp2(S[4 * gg + 1]);
      const float p2 = (mword & (1u << (8 * gg + 2))) ? 0.f : fast_exp2(S[4 * gg + 2]);
      const float p3 = (mword & (1u << (8 * gg + 3))) ? 0.f : fast_exp2(S[4 * gg + 3]);
      c[2 * gg]     = cvt_pk_bf16(p0, p1);   // k = 8g+4hi+{0,1}
      c[2 * gg + 1] = cvt_pk_bf16(p2, p3);   // k = 8g+4hi+{2,3}
    }
    // permlane32_swap(c0,c2): c0 <- {c0.lo, c2.lo} = A-frag word x (k{0,1}|k{8,9})
    //                         c2 <- {c0.hi, c2.hi} = A-frag word z (k{4,5}|k{12,13})
    plswap(c[0], c[2], hi);
    plswap(c[1], c[3], hi);
    plswap(c[4], c[6], hi);
    plswap(c[5], c[7], hi);
    uint4 fa1, fa2;
    fa1.x = c[0]; fa1.y = c[1]; fa1.z = c[2]; fa1.w = c[3];
    fa2.x = c[4]; fa2.y = c[5]; fa2.z = c[6]; fa2.w = c[7];
    short8 A1 = *(const short8*)&fa1;
    short8 A2 = *(const short8*)&fa2;

    // B-frags: cols 0..15 = V[k][d=l31], cols 16..31 = 1.0 (row-sum columns)
    const short8 vb1 = (l31 < 16) ? vraw1 : ones;
    const short8 vb2 = (l31 < 16) ? vraw2 : ones;

    __builtin_amdgcn_s_setprio(1);
    acc = __builtin_amdgcn_mfma_f32_32x32x16_bf16(A1, vb1, acc, 0, 0, 0);
    acc = __builtin_amdgcn_mfma_f32_32x32x16_bf16(A2, vb2, acc, 0, 0, 0);
    __builtin_amdgcn_s_setprio(0);
    kf = kfn;
  }

  // Split-K combine through LDS, then normalize+store (kh==0 waves).
  __syncthreads();
  if (kh) {
    float* dst = Cmb + ((size_t)(qg * 64 + lane)) * 17;
#pragma unroll
    for (int j = 0; j < 16; ++j) dst[j] = acc[j];
  }
  __syncthreads();
  if (!kh) {
    const float* src = Cmb + ((size_t)(qg * 64 + lane)) * 17;
    float o[16];
#pragma unroll
    for (int j = 0; j < 16; ++j) o[j] = acc[j] + src[j];
#pragma unroll
    for (int r = 0; r < 16; ++r) {
      const float s = __shfl_xor(o[r], 16, 64);   // lanes l31<16 receive row sum
      if (l31 < 16) {
        const int q = (r & 3) + 8 * (r >> 2) + 4 * hi;
        ((unsigned short*)XO)[((size_t)(b * 1024 + q0 + q)) * 1024 + h * 16 + l31] =
            f2bf(o[r] * fast_rcp(s));
      }
    }
  }
}

// ---------------------------------------------------------------------------
extern "C" void kernel_launch(void* const* d_in, const int* in_sizes, int n_in,
                              void* d_out, int out_size, void* d_ws, size_t ws_size,
                              hipStream_t stream) {
  const float* query = (const float*)d_in[0];
  const float* key   = (const float*)d_in[1];
  const float* value = (const float*)d_in[2];
  const void*  mask  = d_in[3];
  const float* Wq = (const float*)d_in[4];
  const float* Wk = (const float*)d_in[5];
  const float* Wv = (const float*)d_in[6];
  const float* Wo = (const float*)d_in[7];
  float* out = (float*)d_out;

  char* ws = (char*)d_ws;
  const size_t MB = 1024 * 1024;
  unsigned* mbits = (unsigned*)(ws + 4096);          // 256 KB
  bf16* Qb  = (bf16*)(ws + 4096 + 262144);           // converted inputs, 4 MB each
  bf16* Kb  = Qb + 2 * MB;
  bf16* Vb  = Kb + 2 * MB;
  bf16* Wqb = Vb + 2 * MB;                            // converted weights, 2 MB each
  bf16* Wkb = Wqb + MB;
  bf16* Wvb = Wkb + MB;
  bf16* Wob = Wvb + MB;
  bf16* Qp  = Wob + MB;                               // Q projection, 4 MB
  bf16* KTl = Qp + 2 * MB;                            // K per-head tiles
  bf16* VTl = KTl + 2 * MB;                           // V per-head tiles
  bf16* XO  = VTl + 2 * MB;                           // attn output

  convert_all<<<dim3(1024, 8), 256, 0, stream>>>(query, key, value, Wq, Wk, Wv, Wo,
                                                 Qb, Kb, Vb, Wqb, Wkb, Wvb, Wob,
                                                 (const unsigned char*)mask, (const int*)mask,
                                                 mbits);
  gemm_qkv<<<dim3(16, 16, 3), 256, 0, stream>>>(Qb, Kb, Vb, Wqb, Wkb, Wvb, Qp, KTl, VTl);
  attn_kernel<<<dim3(2048), 256, 0, stream>>>(Qp, KTl, VTl, mbits, XO);
  gemm_out<<<dim3(16, 16), 256, 0, stream>>>(XO, Wob, out);
}

// Round 15
// 87.916 us; speedup vs baseline: 1.0439x; 1.0268x over previous
//
#include <hip/hip_runtime.h>
#include <hip/hip_bf16.h>

// MultiHeadedAttention (namedtensor quirk): 64 heads x dim16, scores /1024,
// bool mask -> -1e9, softmax over keys.
// R15 = R10 verbatim (session best, 88.0us, passed): GEMMs BK=64 with T21
// XOR-swizzle (linear LDS dest for global_load_lds, pre-swizzled GLOBAL source
// granule g^=(row&7), same XOR on the ds_read side); attn = swapped-QK,
// split-K x2, skewed PV pipeline (QK(t) + PV(t-1)), XCD-swizzled grid,
// per-head 1KB K/V tiles, transposed bitpacked mask, fused convert+bitpack.

typedef __hip_bfloat16 bf16;
typedef __attribute__((ext_vector_type(8))) short short8;
typedef __attribute__((ext_vector_type(4))) float f32x4;
typedef __attribute__((ext_vector_type(16))) float f32x16;

__device__ __forceinline__ unsigned short f2bf(float f) {
  union { float f; unsigned u; } x; x.f = f;
  unsigned r = x.u + 0x7FFFu + ((x.u >> 16) & 1u);   // RNE
  return (unsigned short)(r >> 16);
}

__device__ __forceinline__ unsigned cvt_pk_bf16(float lo, float hi) {
  unsigned r;
  asm("v_cvt_pk_bf16_f32 %0, %1, %2" : "=v"(r) : "v"(lo), "v"(hi));
  return r;
}

__device__ __forceinline__ float fast_exp2(float x) {
#if __has_builtin(__builtin_amdgcn_exp2f)
  return __builtin_amdgcn_exp2f(x);
#else
  return __expf(x * 0.6931471805599453f);
#endif
}

// Async global->LDS, 16B per lane.
__device__ __forceinline__ void gload16(const void* g, void* l) {
#if __has_builtin(__builtin_amdgcn_global_load_lds)
  __builtin_amdgcn_global_load_lds(
      (const __attribute__((address_space(1))) unsigned*)g,
      (__attribute__((address_space(3))) unsigned*)l, 16, 0, 0);
#else
  *(uint4*)l = *(const uint4*)g;
#endif
}

// ---------------------------------------------------------------------------
// Fused convert + bitpack. z=0..2 inputs, z=3..6 weights (Wq scaled by
// log2(e)/1024), z=7 mask bitpack with per-block dtype detection.
__global__ void convert_all(
    const float* __restrict__ s0, const float* __restrict__ s1, const float* __restrict__ s2,
    const float* __restrict__ s3, const float* __restrict__ s4, const float* __restrict__ s5,
    const float* __restrict__ s6,
    bf16* __restrict__ d0, bf16* __restrict__ d1, bf16* __restrict__ d2,
    bf16* __restrict__ d3, bf16* __restrict__ d4, bf16* __restrict__ d5,
    bf16* __restrict__ d6,
    const unsigned char* __restrict__ mB, const int* __restrict__ mI,
    unsigned* __restrict__ mout) {
  const int z = blockIdx.y;
  if (z == 7) {
    if (blockIdx.x >= 256) return;
    __shared__ int sflag;
    if (threadIdx.x == 0) sflag = 0;
    __syncthreads();
    const int widx = blockIdx.x * 256 + threadIdx.x;   // 65536 words
    const int row = widx >> 5, kb = widx & 31;
    uchar4 v[8];
    const uchar4* p = (const uchar4*)(mB + (size_t)row * 1024 + kb * 32);
    unsigned any = 0;
#pragma unroll
    for (int j = 0; j < 8; ++j) { v[j] = p[j]; any |= (unsigned)v[j].y | (unsigned)v[j].z | (unsigned)v[j].w; }
    if (__ballot(any != 0)) { if ((threadIdx.x & 63) == 0) atomicOr(&sflag, 1); }
    __syncthreads();
    unsigned bits = 0;
    if (sflag) {   // bool mask
#pragma unroll
      for (int j = 0; j < 8; ++j) {
        bits |= ((unsigned)(v[j].x != 0) << (4 * j)) | ((unsigned)(v[j].y != 0) << (4 * j + 1))
              | ((unsigned)(v[j].z != 0) << (4 * j + 2)) | ((unsigned)(v[j].w != 0) << (4 * j + 3));
      }
    } else {       // int32 mask
      const int4* q = (const int4*)(mI + (size_t)row * 1024 + kb * 32);
#pragma unroll
      for (int j = 0; j < 8; ++j) {
        int4 u = q[j];
        bits |= ((unsigned)(u.x != 0) << (4 * j)) | ((unsigned)(u.y != 0) << (4 * j + 1))
              | ((unsigned)(u.z != 0) << (4 * j + 2)) | ((unsigned)(u.w != 0) << (4 * j + 3));
      }
    }
    const int bq = row >> 10, qb = (row & 1023) >> 5, qr = row & 31;
    mout[((((bq * 32 + qb) * 8 + (kb >> 2)) * 32 + qr) << 2) + (kb & 3)] = bits;
    return;
  }
  const float* s; bf16* d; int n8; float sc = 1.0f;
  if      (z == 0) { s = s0; d = d0; n8 = 262144; }
  else if (z == 1) { s = s1; d = d1; n8 = 262144; }
  else if (z == 2) { s = s2; d = d2; n8 = 262144; }
  else if (z == 3) { s = s3; d = d3; n8 = 131072; sc = 0.0014088818758681283f; }   // log2e/1024
  else if (z == 4) { s = s4; d = d4; n8 = 131072; }
  else if (z == 5) { s = s5; d = d5; n8 = 131072; }
  else             { s = s6; d = d6; n8 = 131072; }
  const int i = blockIdx.x * 256 + threadIdx.x;
  if (i >= n8) return;
  const f32x4* p = (const f32x4*)s + (size_t)i * 2;
  f32x4 a = p[0], b = p[1];
  uint4 o;
  o.x = cvt_pk_bf16(a[0] * sc, a[1] * sc); o.y = cvt_pk_bf16(a[2] * sc, a[3] * sc);
  o.z = cvt_pk_bf16(b[0] * sc, b[1] * sc); o.w = cvt_pk_bf16(b[2] * sc, b[3] * sc);
  ((uint4*)d)[i] = o;
}

// ---------------------------------------------------------------------------
// GEMM C = A * W^T, bf16, 128x64 tile, 4 waves, BK=64.
// Staging: global_load_lds into LINEAR LDS A[128][64], B[64][64]; the SOURCE
// granule is XOR-swizzled (g ^= row&7) so the swizzled ds_read (granule
// (ks*4+kg)^(l15&7)) is bank-conflict-free despite the 128B row wrap.
#define PSTR 36

__global__ __launch_bounds__(256) void gemm_qkv(
    const bf16* __restrict__ A0, const bf16* __restrict__ A1, const bf16* __restrict__ A2,
    const bf16* __restrict__ W0, const bf16* __restrict__ W1, const bf16* __restrict__ W2,
    bf16* __restrict__ C0, bf16* __restrict__ C1, bf16* __restrict__ C2) {
  __shared__ __align__(16) bf16 smem[12288];       // 24KB: A[128][64]+B[64][64]
  bf16* As = smem;
  bf16* Bs = smem + 8192;
  const int z = blockIdx.z;
  const bf16* __restrict__ A = (z == 0) ? A0 : (z == 1) ? A1 : A2;
  const bf16* __restrict__ W = (z == 0) ? W0 : (z == 1) ? W1 : W2;
  bf16* __restrict__ C = (z == 0) ? C0 : (z == 1) ? C1 : C2;
  const int tid = threadIdx.x, lane = tid & 63, w = tid >> 6;
  const int wr = (w >> 1) * 64, wc = (w & 1) * 32;
  const int row0 = blockIdx.y * 128, col0 = blockIdx.x * 64;
  const int l15 = lane & 15, kg = lane >> 4;
  const int l7 = l15 & 7;

  // staging addresses (6 rounds: 4 for A, 2 for B); source granule swizzled.
  const bf16* ga[4]; const bf16* gb[2];
  bf16* la[4]; bf16* lb[2];
#pragma unroll
  for (int r = 0; r < 4; ++r) {
    const int idx = r * 256 + tid, row = idx >> 3, g = idx & 7;
    ga[r] = A + (size_t)(row0 + row) * 1024 + (g ^ (row & 7)) * 8;
    la[r] = As + idx * 8;
  }
#pragma unroll
  for (int r = 0; r < 2; ++r) {
    const int idx = r * 256 + tid, row = idx >> 3, g = idx & 7;
    gb[r] = W + (size_t)(col0 + row) * 1024 + (g ^ (row & 7)) * 8;
    lb[r] = Bs + idx * 8;
  }

  f32x4 acc[4][2];
#pragma unroll
  for (int m = 0; m < 4; ++m)
#pragma unroll
    for (int n = 0; n < 2; ++n)
#pragma unroll
      for (int j = 0; j < 4; ++j) acc[m][n][j] = 0.f;

  for (int t = 0; t < 16; ++t) {
    const int k0 = t * 64;
#pragma unroll
    for (int r = 0; r < 4; ++r) gload16(ga[r] + k0, la[r]);
#pragma unroll
    for (int r = 0; r < 2; ++r) gload16(gb[r] + k0, lb[r]);
    __syncthreads();
    short8 af[4][2], bfr[2][2];
#pragma unroll
    for (int m = 0; m < 4; ++m)
#pragma unroll
      for (int ks = 0; ks < 2; ++ks)
        af[m][ks] = *(const short8*)(&As[(wr + m * 16 + l15) * 64 + ((ks * 4 + kg) ^ l7) * 8]);
#pragma unroll
    for (int n = 0; n < 2; ++n)
#pragma unroll
      for (int ks = 0; ks < 2; ++ks)
        bfr[n][ks] = *(const short8*)(&Bs[(wc + n * 16 + l15) * 64 + ((ks * 4 + kg) ^ l7) * 8]);
#pragma unroll
    for (int ks = 0; ks < 2; ++ks)
#pragma unroll
      for (int m = 0; m < 4; ++m)
#pragma unroll
        for (int n = 0; n < 2; ++n)
          acc[m][n] = __builtin_amdgcn_mfma_f32_16x16x32_bf16(af[m][ks], bfr[n][ks], acc[m][n], 0, 0, 0);
    __syncthreads();
  }

  const int bb = row0 >> 10, srel0 = row0 & 1023;
  if (z == 2) {
    // LDS transpose then coalesced 1KB-tile stores: VT[bh][kb][d(16)][k(32)].
    bf16* T = smem;   // [64 e][136]
#pragma unroll
    for (int m = 0; m < 4; ++m)
#pragma unroll
      for (int n = 0; n < 2; ++n) {
        const int e = wc + n * 16 + l15;
        const int rb = wr + m * 16 + kg * 4;
        uint2 u;
        u.x = cvt_pk_bf16(acc[m][n][0], acc[m][n][1]);
        u.y = cvt_pk_bf16(acc[m][n][2], acc[m][n][3]);
        *(uint2*)(T + e * 136 + rb) = u;
      }
    __syncthreads();
#pragma unroll
    for (int i = 0; i < 4; ++i) {
      const int idx = i * 256 + tid;          // 1024 uint4
      const int tile = idx >> 6, within = idx & 63;
      const int hl = tile >> 2, kbl = tile & 3;
      const int e_sub = within >> 2, kq4 = within & 3;
      uint4 v = *(const uint4*)(T + (hl * 16 + e_sub) * 136 + kbl * 32 + kq4 * 8);
      const int h = (col0 >> 4) + hl;
      const size_t kb = (size_t)((srel0 >> 5) + kbl);
      *(uint4*)((unsigned short*)C + (((size_t)(bb * 64 + h) * 32 + kb) * 512 + e_sub * 32 + kq4 * 8)) = v;
    }
  } else if (z == 1) {
    // KT[bh][kb][k&31][d(16)] direct store.
#pragma unroll
    for (int m = 0; m < 4; ++m)
#pragma unroll
      for (int n = 0; n < 2; ++n) {
        const int ecol = wc + n * 16 + l15;
        const int h = (col0 >> 4) + (ecol >> 4), d = ecol & 15;
#pragma unroll
        for (int j = 0; j < 4; ++j) {
          const int s = srel0 + wr + m * 16 + kg * 4 + j;
          ((unsigned short*)C)[((size_t)(bb * 64 + h) * 32 + (s >> 5)) * 512 + (s & 31) * 16 + d] =
              f2bf(acc[m][n][j]);
        }
      }
  } else {
#pragma unroll
    for (int m = 0; m < 4; ++m)
#pragma unroll
      for (int n = 0; n < 2; ++n) {
        const int col = col0 + wc + n * 16 + l15;
#pragma unroll
        for (int j = 0; j < 4; ++j) {
          const int row = row0 + wr + m * 16 + kg * 4 + j;
          ((unsigned short*)C)[(size_t)row * 1024 + col] = f2bf(acc[m][n][j]);
        }
      }
  }
}

__global__ __launch_bounds__(256) void gemm_out(
    const bf16* __restrict__ A, const bf16* __restrict__ W, float* __restrict__ C) {
  __shared__ __align__(16) bf16 smem[12288];       // A[128][64]+B[64][64]
  bf16* As = smem;
  bf16* Bs = smem + 8192;
  const int tid = threadIdx.x, lane = tid & 63, w = tid >> 6;
  const int wr = (w >> 1) * 64, wc = (w & 1) * 32;
  const int row0 = blockIdx.y * 128, col0 = blockIdx.x * 64;
  const int l15 = lane & 15, kg = lane >> 4;
  const int l7 = l15 & 7;

  const bf16* ga[4]; const bf16* gb[2];
  bf16* la[4]; bf16* lb[2];
#pragma unroll
  for (int r = 0; r < 4; ++r) {
    const int idx = r * 256 + tid, row = idx >> 3, g = idx & 7;
    ga[r] = A + (size_t)(row0 + row) * 1024 + (g ^ (row & 7)) * 8;
    la[r] = As + idx * 8;
  }
#pragma unroll
  for (int r = 0; r < 2; ++r) {
    const int idx = r * 256 + tid, row = idx >> 3, g = idx & 7;
    gb[r] = W + (size_t)(col0 + row) * 1024 + (g ^ (row & 7)) * 8;
    lb[r] = Bs + idx * 8;
  }

  f32x4 acc[4][2];
#pragma unroll
  for (int m = 0; m < 4; ++m)
#pragma unroll
    for (int n = 0; n < 2; ++n)
#pragma unroll
      for (int j = 0; j < 4; ++j) acc[m][n][j] = 0.f;

  for (int t = 0; t < 16; ++t) {
    const int k0 = t * 64;
#pragma unroll
    for (int r = 0; r < 4; ++r) gload16(ga[r] + k0, la[r]);
#pragma unroll
    for (int r = 0; r < 2; ++r) gload16(gb[r] + k0, lb[r]);
    __syncthreads();
    short8 af[4][2], bfr[2][2];
#pragma unroll
    for (int m = 0; m < 4; ++m)
#pragma unroll
      for (int ks = 0; ks < 2; ++ks)
        af[m][ks] = *(const short8*)(&As[(wr + m * 16 + l15) * 64 + ((ks * 4 + kg) ^ l7) * 8]);
#pragma unroll
    for (int n = 0; n < 2; ++n)
#pragma unroll
      for (int ks = 0; ks < 2; ++ks)
        bfr[n][ks] = *(const short8*)(&Bs[(wc + n * 16 + l15) * 64 + ((ks * 4 + kg) ^ l7) * 8]);
#pragma unroll
    for (int ks = 0; ks < 2; ++ks)
#pragma unroll
      for (int m = 0; m < 4; ++m)
#pragma unroll
        for (int n = 0; n < 2; ++n)
          acc[m][n] = __builtin_amdgcn_mfma_f32_16x16x32_bf16(af[m][ks], bfr[n][ks], acc[m][n], 0, 0, 0);
    __syncthreads();
  }

#pragma unroll
  for (int m = 0; m < 4; ++m)
#pragma unroll
    for (int n = 0; n < 2; ++n) {
      const int col = col0 + wc + n * 16 + l15;
#pragma unroll
      for (int j = 0; j < 4; ++j) {
        const int row = row0 + wr + m * 16 + kg * 4 + j;
        C[(size_t)row * 1024 + col] = acc[m][n][j];
      }
    }
}

// ---------------------------------------------------------------------------
// Flash attention (R10): swapped-QK, split-K x2, skewed PV pipeline
// (QK(t) + PV(t-1)), XCD-swizzled 1D grid, wave-contiguous KT/VT 1KB tiles,
// transposed bitpacked mask, P double-buffered in LDS.
__global__ __launch_bounds__(256) void attn_kernel(
    const bf16* __restrict__ Qp, const bf16* __restrict__ KT, const bf16* __restrict__ VT,
    const unsigned* __restrict__ mw, bf16* __restrict__ XO) {
  __shared__ bf16 Pl[4][2][32 * PSTR];   // 18432B; reused as f32 combine area
  const int tid = threadIdx.x, lane = tid & 63, w = tid >> 6;
  const int hi = lane >> 5, l31 = lane & 31, l15 = lane & 15, kg = lane >> 4;
  const int id = blockIdx.x;
  const int xcd = id & 7, grp = (id >> 3) & 15, qt = id >> 7;
  const int g = xcd * 16 + grp;
  const int b = g >> 6, h = g & 63;
  const int qg = w >> 1, kh = w & 1;
  const int q0 = qt * 64 + qg * 32;

  const short8 qf = *(const short8*)(Qp + ((size_t)(b * 1024 + q0 + l31)) * 1024 + h * 16 + hi * 8);
  const bf16* __restrict__ Kb = KT + ((size_t)(b * 64 + h) * 32) * 512;
  const bf16* __restrict__ Vb = VT + ((size_t)(b * 64 + h) * 32) * 512;
  const uint4* __restrict__ Mq =
      (const uint4*)mw + ((size_t)((b * 32 + (q0 >> 5)) * 8 + kh * 4)) * 32 + l31;
  const int sh4 = hi * 4;

  const uint4 mqa = Mq[0], mqb = Mq[32], mqc = Mq[64], mqd = Mq[96];
  const unsigned mm[16] = {mqa.x, mqa.y, mqa.z, mqa.w, mqb.x, mqb.y, mqb.z, mqb.w,
                           mqc.x, mqc.y, mqc.z, mqc.w, mqd.x, mqd.y, mqd.z, mqd.w};

  f32x4 acc0, acc1, sum0, sum1;
#pragma unroll
  for (int j = 0; j < 4; ++j) { acc0[j] = 0.f; acc1[j] = 0.f; sum0[j] = 0.f; sum1[j] = 0.f; }
  f32x16 Z;
#pragma unroll
  for (int i = 0; i < 16; ++i) Z[i] = 0.f;
  short8 ones;
#pragma unroll
  for (int i = 0; i < 8; ++i) ones[i] = (short)0x3F80;   // bf16 1.0

  short8 pa0p, pa1p, vfp;   // operands of the PREVIOUS tile's PV

#pragma unroll
  for (int t = 0; t < 16; ++t) {
    const int kbg = kh * 16 + t;                 // 1KB k-tile index
    const unsigned mword = mm[t] >> sh4;
    const short8 kf = *(const short8*)(Kb + (size_t)kbg * 512 + l31 * 16 + hi * 8);
    f32x16 S = __builtin_amdgcn_mfma_f32_32x32x16_bf16(kf, qf, Z, 0, 0, 0);
    // lane holds S^T[k = kbg*32 + 8g + 4hi + j][q = q0 + l31], reg r = 4g + j

    if (t > 0) {   // PV for tile t-1 (operands loaded last iteration)
      __builtin_amdgcn_s_setprio(1);
      acc0 = __builtin_amdgcn_mfma_f32_16x16x32_bf16(pa0p, vfp, acc0, 0, 0, 0);
      acc1 = __builtin_amdgcn_mfma_f32_16x16x32_bf16(pa1p, vfp, acc1, 0, 0, 0);
      sum0 = __builtin_amdgcn_mfma_f32_16x16x32_bf16(pa0p, ones, sum0, 0, 0, 0);
      sum1 = __builtin_amdgcn_mfma_f32_16x16x32_bf16(pa1p, ones, sum1, 0, 0, 0);
      __builtin_amdgcn_s_setprio(0);
    }

    bf16* pw = &Pl[w][t & 1][l31 * PSTR];
#pragma unroll
    for (int gg = 0; gg < 4; ++gg) {
      float p0, p1, p2, p3;
      p0 = (mword & (1u << (8 * gg + 0))) ? 0.f : fast_exp2(S[4 * gg + 0]);
      p1 = (mword & (1u << (8 * gg + 1))) ? 0.f : fast_exp2(S[4 * gg + 1]);
      p2 = (mword & (1u << (8 * gg + 2))) ? 0.f : fast_exp2(S[4 * gg + 2]);
      p3 = (mword & (1u << (8 * gg + 3))) ? 0.f : fast_exp2(S[4 * gg + 3]);
      uint2 u;
      u.x = cvt_pk_bf16(p0, p1);
      u.y = cvt_pk_bf16(p2, p3);
      *(uint2*)(pw + 8 * gg + 4 * hi) = u;
    }

    vfp  = *(const short8*)(Vb + (size_t)kbg * 512 + l15 * 32 + kg * 8);
    pa0p = *(const short8*)(&Pl[w][t & 1][l15 * PSTR + kg * 8]);
    pa1p = *(const short8*)(&Pl[w][t & 1][(16 + l15) * PSTR + kg * 8]);
  }

  // epilogue PV for tile 15
  __builtin_amdgcn_s_setprio(1);
  acc0 = __builtin_amdgcn_mfma_f32_16x16x32_bf16(pa0p, vfp, acc0, 0, 0, 0);
  acc1 = __builtin_amdgcn_mfma_f32_16x16x32_bf16(pa1p, vfp, acc1, 0, 0, 0);
  sum0 = __builtin_amdgcn_mfma_f32_16x16x32_bf16(pa0p, ones, sum0, 0, 0, 0);
  sum1 = __builtin_amdgcn_mfma_f32_16x16x32_bf16(pa1p, ones, sum1, 0, 0, 0);
  __builtin_amdgcn_s_setprio(0);

  // Combine k-halves through LDS (reuse Pl after a barrier).
  float* fl = (float*)&Pl[0][0][0];
  __syncthreads();
  if (kh) {
    float* dst = fl + ((size_t)(qg * 64 + lane)) * 16;
#pragma unroll
    for (int j = 0; j < 4; ++j) {
      dst[j] = acc0[j]; dst[4 + j] = acc1[j]; dst[8 + j] = sum0[j]; dst[12 + j] = sum1[j];
    }
  }
  __syncthreads();
  if (!kh) {
    const float* src = fl + ((size_t)(qg * 64 + lane)) * 16;
#pragma unroll
    for (int j = 0; j < 4; ++j) {
      const float o0 = acc0[j] + src[j],      d0 = sum0[j] + src[8 + j];
      const float o1 = acc1[j] + src[4 + j],  d1 = sum1[j] + src[12 + j];
      const size_t colo = (size_t)h * 16 + l15;
      ((unsigned short*)XO)[((size_t)(b * 1024 + q0 + kg * 4 + j)) * 1024 + colo] = f2bf(o0 / d0);
      ((unsigned short*)XO)[((size_t)(b * 1024 + q0 + 16 + kg * 4 + j)) * 1024 + colo] = f2bf(o1 / d1);
    }
  }
}

// ---------------------------------------------------------------------------
extern "C" void kernel_launch(void* const* d_in, const int* in_sizes, int n_in,
                              void* d_out, int out_size, void* d_ws, size_t ws_size,
                              hipStream_t stream) {
  const float* query = (const float*)d_in[0];
  const float* key   = (const float*)d_in[1];
  const float* value = (const float*)d_in[2];
  const void*  mask  = d_in[3];
  const float* Wq = (const float*)d_in[4];
  const float* Wk = (const float*)d_in[5];
  const float* Wv = (const float*)d_in[6];
  const float* Wo = (const float*)d_in[7];
  float* out = (float*)d_out;

  char* ws = (char*)d_ws;
  const size_t MB = 1024 * 1024;
  unsigned* mbits = (unsigned*)(ws + 4096);          // 256 KB
  bf16* Qb  = (bf16*)(ws + 4096 + 262144);           // converted inputs, 4 MB each
  bf16* Kb  = Qb + 2 * MB;
  bf16* Vb  = Kb + 2 * MB;
  bf16* Wqb = Vb + 2 * MB;                            // converted weights, 2 MB each
  bf16* Wkb = Wqb + MB;
  bf16* Wvb = Wkb + MB;
  bf16* Wob = Wvb + MB;
  bf16* Qp  = Wob + MB;                               // Q projection, 4 MB
  bf16* KTl = Qp + 2 * MB;                            // K per-head tiles
  bf16* VTl = KTl + 2 * MB;                           // V per-head tiles
  bf16* XO  = VTl + 2 * MB;                           // attn output

  convert_all<<<dim3(1024, 8), 256, 0, stream>>>(query, key, value, Wq, Wk, Wv, Wo,
                                                 Qb, Kb, Vb, Wqb, Wkb, Wvb, Wob,
                                                 (const unsigned char*)mask, (const int*)mask,
                                                 mbits);
  gemm_qkv<<<dim3(16, 16, 3), 256, 0, stream>>>(Qb, Kb, Vb, Wqb, Wkb, Wvb, Qp, KTl, VTl);
  attn_kernel<<<dim3(2048), 256, 0, stream>>>(Qp, KTl, VTl, mbits, XO);
  gemm_out<<<dim3(16, 16), 256, 0, stream>>>(XO, Wob, out);
}

// Round 16
// 87.521 us; speedup vs baseline: 1.0487x; 1.0045x over previous
//
#include <hip/hip_runtime.h>
#include <hip/hip_bf16.h>

// MultiHeadedAttention (namedtensor quirk): 64 heads x dim16, scores /1024,
// bool mask -> -1e9, softmax over keys.
// R16 = R15/R10 (session best, 87.9us) + epilogue divide->rcp (TRANS pipe).
// GEMMs BK=64 with T21 XOR-swizzle (linear LDS dest for global_load_lds,
// pre-swizzled GLOBAL source granule g^=(row&7), same XOR on ds_read); attn =
// swapped-QK, split-K x2, skewed PV pipeline (QK(t)+PV(t-1)), XCD-swizzled
// grid, per-head 1KB K/V tiles, transposed bitpacked mask, fused convert.

typedef __hip_bfloat16 bf16;
typedef __attribute__((ext_vector_type(8))) short short8;
typedef __attribute__((ext_vector_type(4))) float f32x4;
typedef __attribute__((ext_vector_type(16))) float f32x16;

__device__ __forceinline__ unsigned short f2bf(float f) {
  union { float f; unsigned u; } x; x.f = f;
  unsigned r = x.u + 0x7FFFu + ((x.u >> 16) & 1u);   // RNE
  return (unsigned short)(r >> 16);
}

__device__ __forceinline__ unsigned cvt_pk_bf16(float lo, float hi) {
  unsigned r;
  asm("v_cvt_pk_bf16_f32 %0, %1, %2" : "=v"(r) : "v"(lo), "v"(hi));
  return r;
}

__device__ __forceinline__ float fast_exp2(float x) {
#if __has_builtin(__builtin_amdgcn_exp2f)
  return __builtin_amdgcn_exp2f(x);
#else
  return __expf(x * 0.6931471805599453f);
#endif
}

__device__ __forceinline__ float fast_rcp(float x) {
#if __has_builtin(__builtin_amdgcn_rcpf)
  return __builtin_amdgcn_rcpf(x);
#else
  return 1.0f / x;
#endif
}

// Async global->LDS, 16B per lane.
__device__ __forceinline__ void gload16(const void* g, void* l) {
#if __has_builtin(__builtin_amdgcn_global_load_lds)
  __builtin_amdgcn_global_load_lds(
      (const __attribute__((address_space(1))) unsigned*)g,
      (__attribute__((address_space(3))) unsigned*)l, 16, 0, 0);
#else
  *(uint4*)l = *(const uint4*)g;
#endif
}

// ---------------------------------------------------------------------------
// Fused convert + bitpack. z=0..2 inputs, z=3..6 weights (Wq scaled by
// log2(e)/1024), z=7 mask bitpack with per-block dtype detection.
__global__ void convert_all(
    const float* __restrict__ s0, const float* __restrict__ s1, const float* __restrict__ s2,
    const float* __restrict__ s3, const float* __restrict__ s4, const float* __restrict__ s5,
    const float* __restrict__ s6,
    bf16* __restrict__ d0, bf16* __restrict__ d1, bf16* __restrict__ d2,
    bf16* __restrict__ d3, bf16* __restrict__ d4, bf16* __restrict__ d5,
    bf16* __restrict__ d6,
    const unsigned char* __restrict__ mB, const int* __restrict__ mI,
    unsigned* __restrict__ mout) {
  const int z = blockIdx.y;
  if (z == 7) {
    if (blockIdx.x >= 256) return;
    __shared__ int sflag;
    if (threadIdx.x == 0) sflag = 0;
    __syncthreads();
    const int widx = blockIdx.x * 256 + threadIdx.x;   // 65536 words
    const int row = widx >> 5, kb = widx & 31;
    uchar4 v[8];
    const uchar4* p = (const uchar4*)(mB + (size_t)row * 1024 + kb * 32);
    unsigned any = 0;
#pragma unroll
    for (int j = 0; j < 8; ++j) { v[j] = p[j]; any |= (unsigned)v[j].y | (unsigned)v[j].z | (unsigned)v[j].w; }
    if (__ballot(any != 0)) { if ((threadIdx.x & 63) == 0) atomicOr(&sflag, 1); }
    __syncthreads();
    unsigned bits = 0;
    if (sflag) {   // bool mask
#pragma unroll
      for (int j = 0; j < 8; ++j) {
        bits |= ((unsigned)(v[j].x != 0) << (4 * j)) | ((unsigned)(v[j].y != 0) << (4 * j + 1))
              | ((unsigned)(v[j].z != 0) << (4 * j + 2)) | ((unsigned)(v[j].w != 0) << (4 * j + 3));
      }
    } else {       // int32 mask
      const int4* q = (const int4*)(mI + (size_t)row * 1024 + kb * 32);
#pragma unroll
      for (int j = 0; j < 8; ++j) {
        int4 u = q[j];
        bits |= ((unsigned)(u.x != 0) << (4 * j)) | ((unsigned)(u.y != 0) << (4 * j + 1))
              | ((unsigned)(u.z != 0) << (4 * j + 2)) | ((unsigned)(u.w != 0) << (4 * j + 3));
      }
    }
    const int bq = row >> 10, qb = (row & 1023) >> 5, qr = row & 31;
    mout[((((bq * 32 + qb) * 8 + (kb >> 2)) * 32 + qr) << 2) + (kb & 3)] = bits;
    return;
  }
  const float* s; bf16* d; int n8; float sc = 1.0f;
  if      (z == 0) { s = s0; d = d0; n8 = 262144; }
  else if (z == 1) { s = s1; d = d1; n8 = 262144; }
  else if (z == 2) { s = s2; d = d2; n8 = 262144; }
  else if (z == 3) { s = s3; d = d3; n8 = 131072; sc = 0.0014088818758681283f; }   // log2e/1024
  else if (z == 4) { s = s4; d = d4; n8 = 131072; }
  else if (z == 5) { s = s5; d = d5; n8 = 131072; }
  else             { s = s6; d = d6; n8 = 131072; }
  const int i = blockIdx.x * 256 + threadIdx.x;
  if (i >= n8) return;
  const f32x4* p = (const f32x4*)s + (size_t)i * 2;
  f32x4 a = p[0], b = p[1];
  uint4 o;
  o.x = cvt_pk_bf16(a[0] * sc, a[1] * sc); o.y = cvt_pk_bf16(a[2] * sc, a[3] * sc);
  o.z = cvt_pk_bf16(b[0] * sc, b[1] * sc); o.w = cvt_pk_bf16(b[2] * sc, b[3] * sc);
  ((uint4*)d)[i] = o;
}

// ---------------------------------------------------------------------------
// GEMM C = A * W^T, bf16, 128x64 tile, 4 waves, BK=64.
// Staging: global_load_lds into LINEAR LDS A[128][64], B[64][64]; the SOURCE
// granule is XOR-swizzled (g ^= row&7) so the swizzled ds_read (granule
// (ks*4+kg)^(l15&7)) is bank-conflict-free despite the 128B row wrap.
#define PSTR 36

__global__ __launch_bounds__(256) void gemm_qkv(
    const bf16* __restrict__ A0, const bf16* __restrict__ A1, const bf16* __restrict__ A2,
    const bf16* __restrict__ W0, const bf16* __restrict__ W1, const bf16* __restrict__ W2,
    bf16* __restrict__ C0, bf16* __restrict__ C1, bf16* __restrict__ C2) {
  __shared__ __align__(16) bf16 smem[12288];       // 24KB: A[128][64]+B[64][64]
  bf16* As = smem;
  bf16* Bs = smem + 8192;
  const int z = blockIdx.z;
  const bf16* __restrict__ A = (z == 0) ? A0 : (z == 1) ? A1 : A2;
  const bf16* __restrict__ W = (z == 0) ? W0 : (z == 1) ? W1 : W2;
  bf16* __restrict__ C = (z == 0) ? C0 : (z == 1) ? C1 : C2;
  const int tid = threadIdx.x, lane = tid & 63, w = tid >> 6;
  const int wr = (w >> 1) * 64, wc = (w & 1) * 32;
  const int row0 = blockIdx.y * 128, col0 = blockIdx.x * 64;
  const int l15 = lane & 15, kg = lane >> 4;
  const int l7 = l15 & 7;

  // staging addresses (6 rounds: 4 for A, 2 for B); source granule swizzled.
  const bf16* ga[4]; const bf16* gb[2];
  bf16* la[4]; bf16* lb[2];
#pragma unroll
  for (int r = 0; r < 4; ++r) {
    const int idx = r * 256 + tid, row = idx >> 3, g = idx & 7;
    ga[r] = A + (size_t)(row0 + row) * 1024 + (g ^ (row & 7)) * 8;
    la[r] = As + idx * 8;
  }
#pragma unroll
  for (int r = 0; r < 2; ++r) {
    const int idx = r * 256 + tid, row = idx >> 3, g = idx & 7;
    gb[r] = W + (size_t)(col0 + row) * 1024 + (g ^ (row & 7)) * 8;
    lb[r] = Bs + idx * 8;
  }

  f32x4 acc[4][2];
#pragma unroll
  for (int m = 0; m < 4; ++m)
#pragma unroll
    for (int n = 0; n < 2; ++n)
#pragma unroll
      for (int j = 0; j < 4; ++j) acc[m][n][j] = 0.f;

  for (int t = 0; t < 16; ++t) {
    const int k0 = t * 64;
#pragma unroll
    for (int r = 0; r < 4; ++r) gload16(ga[r] + k0, la[r]);
#pragma unroll
    for (int r = 0; r < 2; ++r) gload16(gb[r] + k0, lb[r]);
    __syncthreads();
    short8 af[4][2], bfr[2][2];
#pragma unroll
    for (int m = 0; m < 4; ++m)
#pragma unroll
      for (int ks = 0; ks < 2; ++ks)
        af[m][ks] = *(const short8*)(&As[(wr + m * 16 + l15) * 64 + ((ks * 4 + kg) ^ l7) * 8]);
#pragma unroll
    for (int n = 0; n < 2; ++n)
#pragma unroll
      for (int ks = 0; ks < 2; ++ks)
        bfr[n][ks] = *(const short8*)(&Bs[(wc + n * 16 + l15) * 64 + ((ks * 4 + kg) ^ l7) * 8]);
#pragma unroll
    for (int ks = 0; ks < 2; ++ks)
#pragma unroll
      for (int m = 0; m < 4; ++m)
#pragma unroll
        for (int n = 0; n < 2; ++n)
          acc[m][n] = __builtin_amdgcn_mfma_f32_16x16x32_bf16(af[m][ks], bfr[n][ks], acc[m][n], 0, 0, 0);
    __syncthreads();
  }

  const int bb = row0 >> 10, srel0 = row0 & 1023;
  if (z == 2) {
    // LDS transpose then coalesced 1KB-tile stores: VT[bh][kb][d(16)][k(32)].
    bf16* T = smem;   // [64 e][136]
#pragma unroll
    for (int m = 0; m < 4; ++m)
#pragma unroll
      for (int n = 0; n < 2; ++n) {
        const int e = wc + n * 16 + l15;
        const int rb = wr + m * 16 + kg * 4;
        uint2 u;
        u.x = cvt_pk_bf16(acc[m][n][0], acc[m][n][1]);
        u.y = cvt_pk_bf16(acc[m][n][2], acc[m][n][3]);
        *(uint2*)(T + e * 136 + rb) = u;
      }
    __syncthreads();
#pragma unroll
    for (int i = 0; i < 4; ++i) {
      const int idx = i * 256 + tid;          // 1024 uint4
      const int tile = idx >> 6, within = idx & 63;
      const int hl = tile >> 2, kbl = tile & 3;
      const int e_sub = within >> 2, kq4 = within & 3;
      uint4 v = *(const uint4*)(T + (hl * 16 + e_sub) * 136 + kbl * 32 + kq4 * 8);
      const int h = (col0 >> 4) + hl;
      const size_t kb = (size_t)((srel0 >> 5) + kbl);
      *(uint4*)((unsigned short*)C + (((size_t)(bb * 64 + h) * 32 + kb) * 512 + e_sub * 32 + kq4 * 8)) = v;
    }
  } else if (z == 1) {
    // KT[bh][kb][k&31][d(16)] direct store.
#pragma unroll
    for (int m = 0; m < 4; ++m)
#pragma unroll
      for (int n = 0; n < 2; ++n) {
        const int ecol = wc + n * 16 + l15;
        const int h = (col0 >> 4) + (ecol >> 4), d = ecol & 15;
#pragma unroll
        for (int j = 0; j < 4; ++j) {
          const int s = srel0 + wr + m * 16 + kg * 4 + j;
          ((unsigned short*)C)[((size_t)(bb * 64 + h) * 32 + (s >> 5)) * 512 + (s & 31) * 16 + d] =
              f2bf(acc[m][n][j]);
        }
      }
  } else {
#pragma unroll
    for (int m = 0; m < 4; ++m)
#pragma unroll
      for (int n = 0; n < 2; ++n) {
        const int col = col0 + wc + n * 16 + l15;
#pragma unroll
        for (int j = 0; j < 4; ++j) {
          const int row = row0 + wr + m * 16 + kg * 4 + j;
          ((unsigned short*)C)[(size_t)row * 1024 + col] = f2bf(acc[m][n][j]);
        }
      }
  }
}

__global__ __launch_bounds__(256) void gemm_out(
    const bf16* __restrict__ A, const bf16* __restrict__ W, float* __restrict__ C) {
  __shared__ __align__(16) bf16 smem[12288];       // A[128][64]+B[64][64]
  bf16* As = smem;
  bf16* Bs = smem + 8192;
  const int tid = threadIdx.x, lane = tid & 63, w = tid >> 6;
  const int wr = (w >> 1) * 64, wc = (w & 1) * 32;
  const int row0 = blockIdx.y * 128, col0 = blockIdx.x * 64;
  const int l15 = lane & 15, kg = lane >> 4;
  const int l7 = l15 & 7;

  const bf16* ga[4]; const bf16* gb[2];
  bf16* la[4]; bf16* lb[2];
#pragma unroll
  for (int r = 0; r < 4; ++r) {
    const int idx = r * 256 + tid, row = idx >> 3, g = idx & 7;
    ga[r] = A + (size_t)(row0 + row) * 1024 + (g ^ (row & 7)) * 8;
    la[r] = As + idx * 8;
  }
#pragma unroll
  for (int r = 0; r < 2; ++r) {
    const int idx = r * 256 + tid, row = idx >> 3, g = idx & 7;
    gb[r] = W + (size_t)(col0 + row) * 1024 + (g ^ (row & 7)) * 8;
    lb[r] = Bs + idx * 8;
  }

  f32x4 acc[4][2];
#pragma unroll
  for (int m = 0; m < 4; ++m)
#pragma unroll
    for (int n = 0; n < 2; ++n)
#pragma unroll
      for (int j = 0; j < 4; ++j) acc[m][n][j] = 0.f;

  for (int t = 0; t < 16; ++t) {
    const int k0 = t * 64;
#pragma unroll
    for (int r = 0; r < 4; ++r) gload16(ga[r] + k0, la[r]);
#pragma unroll
    for (int r = 0; r < 2; ++r) gload16(gb[r] + k0, lb[r]);
    __syncthreads();
    short8 af[4][2], bfr[2][2];
#pragma unroll
    for (int m = 0; m < 4; ++m)
#pragma unroll
      for (int ks = 0; ks < 2; ++ks)
        af[m][ks] = *(const short8*)(&As[(wr + m * 16 + l15) * 64 + ((ks * 4 + kg) ^ l7) * 8]);
#pragma unroll
    for (int n = 0; n < 2; ++n)
#pragma unroll
      for (int ks = 0; ks < 2; ++ks)
        bfr[n][ks] = *(const short8*)(&Bs[(wc + n * 16 + l15) * 64 + ((ks * 4 + kg) ^ l7) * 8]);
#pragma unroll
    for (int ks = 0; ks < 2; ++ks)
#pragma unroll
      for (int m = 0; m < 4; ++m)
#pragma unroll
        for (int n = 0; n < 2; ++n)
          acc[m][n] = __builtin_amdgcn_mfma_f32_16x16x32_bf16(af[m][ks], bfr[n][ks], acc[m][n], 0, 0, 0);
    __syncthreads();
  }

#pragma unroll
  for (int m = 0; m < 4; ++m)
#pragma unroll
    for (int n = 0; n < 2; ++n) {
      const int col = col0 + wc + n * 16 + l15;
#pragma unroll
      for (int j = 0; j < 4; ++j) {
        const int row = row0 + wr + m * 16 + kg * 4 + j;
        C[(size_t)row * 1024 + col] = acc[m][n][j];
      }
    }
}

// ---------------------------------------------------------------------------
// Flash attention (R10): swapped-QK, split-K x2, skewed PV pipeline
// (QK(t) + PV(t-1)), XCD-swizzled 1D grid, wave-contiguous KT/VT 1KB tiles,
// transposed bitpacked mask, P double-buffered in LDS. Epilogue uses rcp+mul
// (TRANS pipe) instead of f32 divide sequences.
__global__ __launch_bounds__(256) void attn_kernel(
    const bf16* __restrict__ Qp, const bf16* __restrict__ KT, const bf16* __restrict__ VT,
    const unsigned* __restrict__ mw, bf16* __restrict__ XO) {
  __shared__ bf16 Pl[4][2][32 * PSTR];   // 18432B; reused as f32 combine area
  const int tid = threadIdx.x, lane = tid & 63, w = tid >> 6;
  const int hi = lane >> 5, l31 = lane & 31, l15 = lane & 15, kg = lane >> 4;
  const int id = blockIdx.x;
  const int xcd = id & 7, grp = (id >> 3) & 15, qt = id >> 7;
  const int g = xcd * 16 + grp;
  const int b = g >> 6, h = g & 63;
  const int qg = w >> 1, kh = w & 1;
  const int q0 = qt * 64 + qg * 32;

  const short8 qf = *(const short8*)(Qp + ((size_t)(b * 1024 + q0 + l31)) * 1024 + h * 16 + hi * 8);
  const bf16* __restrict__ Kb = KT + ((size_t)(b * 64 + h) * 32) * 512;
  const bf16* __restrict__ Vb = VT + ((size_t)(b * 64 + h) * 32) * 512;
  const uint4* __restrict__ Mq =
      (const uint4*)mw + ((size_t)((b * 32 + (q0 >> 5)) * 8 + kh * 4)) * 32 + l31;
  const int sh4 = hi * 4;

  const uint4 mqa = Mq[0], mqb = Mq[32], mqc = Mq[64], mqd = Mq[96];
  const unsigned mm[16] = {mqa.x, mqa.y, mqa.z, mqa.w, mqb.x, mqb.y, mqb.z, mqb.w,
                           mqc.x, mqc.y, mqc.z, mqc.w, mqd.x, mqd.y, mqd.z, mqd.w};

  f32x4 acc0, acc1, sum0, sum1;
#pragma unroll
  for (int j = 0; j < 4; ++j) { acc0[j] = 0.f; acc1[j] = 0.f; sum0[j] = 0.f; sum1[j] = 0.f; }
  f32x16 Z;
#pragma unroll
  for (int i = 0; i < 16; ++i) Z[i] = 0.f;
  short8 ones;
#pragma unroll
  for (int i = 0; i < 8; ++i) ones[i] = (short)0x3F80;   // bf16 1.0

  short8 pa0p, pa1p, vfp;   // operands of the PREVIOUS tile's PV

#pragma unroll
  for (int t = 0; t < 16; ++t) {
    const int kbg = kh * 16 + t;                 // 1KB k-tile index
    const unsigned mword = mm[t] >> sh4;
    const short8 kf = *(const short8*)(Kb + (size_t)kbg * 512 + l31 * 16 + hi * 8);
    f32x16 S = __builtin_amdgcn_mfma_f32_32x32x16_bf16(kf, qf, Z, 0, 0, 0);
    // lane holds S^T[k = kbg*32 + 8g + 4hi + j][q = q0 + l31], reg r = 4g + j

    if (t > 0) {   // PV for tile t-1 (operands loaded last iteration)
      __builtin_amdgcn_s_setprio(1);
      acc0 = __builtin_amdgcn_mfma_f32_16x16x32_bf16(pa0p, vfp, acc0, 0, 0, 0);
      acc1 = __builtin_amdgcn_mfma_f32_16x16x32_bf16(pa1p, vfp, acc1, 0, 0, 0);
      sum0 = __builtin_amdgcn_mfma_f32_16x16x32_bf16(pa0p, ones, sum0, 0, 0, 0);
      sum1 = __builtin_amdgcn_mfma_f32_16x16x32_bf16(pa1p, ones, sum1, 0, 0, 0);
      __builtin_amdgcn_s_setprio(0);
    }

    bf16* pw = &Pl[w][t & 1][l31 * PSTR];
#pragma unroll
    for (int gg = 0; gg < 4; ++gg) {
      float p0, p1, p2, p3;
      p0 = (mword & (1u << (8 * gg + 0))) ? 0.f : fast_exp2(S[4 * gg + 0]);
      p1 = (mword & (1u << (8 * gg + 1))) ? 0.f : fast_exp2(S[4 * gg + 1]);
      p2 = (mword & (1u << (8 * gg + 2))) ? 0.f : fast_exp2(S[4 * gg + 2]);
      p3 = (mword & (1u << (8 * gg + 3))) ? 0.f : fast_exp2(S[4 * gg + 3]);
      uint2 u;
      u.x = cvt_pk_bf16(p0, p1);
      u.y = cvt_pk_bf16(p2, p3);
      *(uint2*)(pw + 8 * gg + 4 * hi) = u;
    }

    vfp  = *(const short8*)(Vb + (size_t)kbg * 512 + l15 * 32 + kg * 8);
    pa0p = *(const short8*)(&Pl[w][t & 1][l15 * PSTR + kg * 8]);
    pa1p = *(const short8*)(&Pl[w][t & 1][(16 + l15) * PSTR + kg * 8]);
  }

  // epilogue PV for tile 15
  __builtin_amdgcn_s_setprio(1);
  acc0 = __builtin_amdgcn_mfma_f32_16x16x32_bf16(pa0p, vfp, acc0, 0, 0, 0);
  acc1 = __builtin_amdgcn_mfma_f32_16x16x32_bf16(pa1p, vfp, acc1, 0, 0, 0);
  sum0 = __builtin_amdgcn_mfma_f32_16x16x32_bf16(pa0p, ones, sum0, 0, 0, 0);
  sum1 = __builtin_amdgcn_mfma_f32_16x16x32_bf16(pa1p, ones, sum1, 0, 0, 0);
  __builtin_amdgcn_s_setprio(0);

  // Combine k-halves through LDS (reuse Pl after a barrier).
  float* fl = (float*)&Pl[0][0][0];
  __syncthreads();
  if (kh) {
    float* dst = fl + ((size_t)(qg * 64 + lane)) * 16;
#pragma unroll
    for (int j = 0; j < 4; ++j) {
      dst[j] = acc0[j]; dst[4 + j] = acc1[j]; dst[8 + j] = sum0[j]; dst[12 + j] = sum1[j];
    }
  }
  __syncthreads();
  if (!kh) {
    const float* src = fl + ((size_t)(qg * 64 + lane)) * 16;
#pragma unroll
    for (int j = 0; j < 4; ++j) {
      const float o0 = acc0[j] + src[j],      d0 = sum0[j] + src[8 + j];
      const float o1 = acc1[j] + src[4 + j],  d1 = sum1[j] + src[12 + j];
      const size_t colo = (size_t)h * 16 + l15;
      ((unsigned short*)XO)[((size_t)(b * 1024 + q0 + kg * 4 + j)) * 1024 + colo] =
          f2bf(o0 * fast_rcp(d0));
      ((unsigned short*)XO)[((size_t)(b * 1024 + q0 + 16 + kg * 4 + j)) * 1024 + colo] =
          f2bf(o1 * fast_rcp(d1));
    }
  }
}

// ---------------------------------------------------------------------------
extern "C" void kernel_launch(void* const* d_in, const int* in_sizes, int n_in,
                              void* d_out, int out_size, void* d_ws, size_t ws_size,
                              hipStream_t stream) {
  const float* query = (const float*)d_in[0];
  const float* key   = (const float*)d_in[1];
  const float* value = (const float*)d_in[2];
  const void*  mask  = d_in[3];
  const float* Wq = (const float*)d_in[4];
  const float* Wk = (const float*)d_in[5];
  const float* Wv = (const float*)d_in[6];
  const float* Wo = (const float*)d_in[7];
  float* out = (float*)d_out;

  char* ws = (char*)d_ws;
  const size_t MB = 1024 * 1024;
  unsigned* mbits = (unsigned*)(ws + 4096);          // 256 KB
  bf16* Qb  = (bf16*)(ws + 4096 + 262144);           // converted inputs, 4 MB each
  bf16* Kb  = Qb + 2 * MB;
  bf16* Vb  = Kb + 2 * MB;
  bf16* Wqb = Vb + 2 * MB;                            // converted weights, 2 MB each
  bf16* Wkb = Wqb + MB;
  bf16* Wvb = Wkb + MB;
  bf16* Wob = Wvb + MB;
  bf16* Qp  = Wob + MB;                               // Q projection, 4 MB
  bf16* KTl = Qp + 2 * MB;                            // K per-head tiles
  bf16* VTl = KTl + 2 * MB;                           // V per-head tiles
  bf16* XO  = VTl + 2 * MB;                           // attn output

  convert_all<<<dim3(1024, 8), 256, 0, stream>>>(query, key, value, Wq, Wk, Wv, Wo,
                                                 Qb, Kb, Vb, Wqb, Wkb, Wvb, Wob,
                                                 (const unsigned char*)mask, (const int*)mask,
                                                 mbits);
  gemm_qkv<<<dim3(16, 16, 3), 256, 0, stream>>>(Qb, Kb, Vb, Wqb, Wkb, Wvb, Qp, KTl, VTl);
  attn_kernel<<<dim3(2048), 256, 0, stream>>>(Qp, KTl, VTl, mbits, XO);
  gemm_out<<<dim3(16, 16), 256, 0, stream>>>(XO, Wob, out);
}